// Round 3
// baseline (411.652 us; speedup 1.0000x reference)
//
#include <hip/hip_runtime.h>
#include <math.h>

// ---------------------------------------------------------------------------
// GraphConvolution: B=2, N=50000, D=64, E=800000, H=32
// R3: k_gemm = register GEMM (W col in 64 VGPRs, x broadcast via v_readlane,
//     zero LDS); k_dots = per-thread-row dots + gate (no shuffles);
//     single-dispatch block scan; k_row phase2 scalarized (readlane -> SGPR
//     col/weight, scalar-pipe addressing). 7 dispatches total.
// ---------------------------------------------------------------------------

__device__ __forceinline__ float elu_f(float x) {
    return x > 0.f ? x : __expf(x) - 1.f;
}

__device__ __forceinline__ float rl_f(float v, int k) {
    return __uint_as_float(__builtin_amdgcn_readlane(__float_as_uint(v), k));
}

// --- tf = x_infl @ W : wave = 32 rows, lane = output column ---
__global__ __launch_bounds__(256) void k_gemm(
    const float* __restrict__ x_infl, const float* __restrict__ Wg,
    float* __restrict__ tf, int BN)
{
    int lane = threadIdx.x & 63;
    int wid  = __builtin_amdgcn_readfirstlane(threadIdx.x >> 6);
    int rbase = (blockIdx.x * 4 + wid) * 32;

    float wcol[64];                        // W[:, lane]
#pragma unroll
    for (int k = 0; k < 64; ++k) wcol[k] = Wg[k * 64 + lane];

    for (int bb = 0; bb < 4; ++bb) {       // 4 batches of 8 rows
        int r0 = rbase + bb * 8;
        float xb[8], acc[8];
#pragma unroll
        for (int i = 0; i < 8; ++i) {
            int rr = r0 + i; rr = (rr < BN) ? rr : BN - 1;
            xb[i] = x_infl[((size_t)rr << 6) + lane];   // xb[i] lane k = x[r0+i][k]
            acc[i] = 0.f;
        }
#pragma unroll
        for (int k = 0; k < 64; ++k) {
#pragma unroll
            for (int i = 0; i < 8; ++i)
                acc[i] = fmaf(rl_f(xb[i], k), wcol[k], acc[i]);
        }
#pragma unroll
        for (int i = 0; i < 8; ++i)
            if (r0 + i < BN) tf[(size_t)(r0 + i) * 64 + lane] = acc[i];
    }
}

// --- per-row dots (s_r,s_c,e_r,e_c) + gate MLP; thread = row ---
__global__ __launch_bounds__(256) void k_dots(
    const float* __restrict__ tf, const float* __restrict__ x_state,
    const float* __restrict__ sbeta, const float* __restrict__ iatt,
    const float* __restrict__ w1, const float* __restrict__ b1,
    const float* __restrict__ w2, const float* __restrict__ b2,
    float4* __restrict__ node4, float2* __restrict__ rpack, int BN)
{
    int r = blockIdx.x * 256 + threadIdx.x;
    int rr = (r < BN) ? r : BN - 1;
    const float* t = tf + ((size_t)rr << 6);

    float srv = 0.f, scv = 0.f, erv = 0.f, ecv = 0.f;
#pragma unroll
    for (int k = 0; k < 64; k += 4) {
        float4 tv  = *(const float4*)(t + k);
        float4 bsr = *(const float4*)(sbeta + k);
        float4 bsc = *(const float4*)(sbeta + 64 + k);
        float4 ber = *(const float4*)(iatt + k);
        float4 bec = *(const float4*)(iatt + 64 + k);
        srv += tv.x * bsr.x + tv.y * bsr.y + tv.z * bsr.z + tv.w * bsr.w;
        scv += tv.x * bsc.x + tv.y * bsc.y + tv.z * bsc.z + tv.w * bsc.w;
        erv += tv.x * ber.x + tv.y * ber.y + tv.z * ber.z + tv.w * ber.w;
        ecv += tv.x * bec.x + tv.y * bec.y + tv.z * bec.z + tv.w * bec.w;
    }

    float xs = x_state[rr];
    float tacc = b2[0];
#pragma unroll
    for (int h = 0; h < 32; ++h)
        tacc = fmaf(elu_f(fmaf(xs, w1[h], b1[h])), w2[h], tacc);
    float gate = elu_f(tacc);

    if (r < BN) {
        node4[r] = make_float4(ecv, scv, xs, gate);   // {e_c, s_c, xs, gate}
        rpack[r] = make_float2(erv, srv);             // {e_r, s_r}
    }
}

// --- CSR build ---
__global__ __launch_bounds__(256) void k_hist(const int2* __restrict__ Li,
                                              int* __restrict__ counts, int E) {
    int e = blockIdx.x * 256 + threadIdx.x;
    if (e < E) atomicAdd(&counts[Li[e].x], 1);
}

// single-dispatch exclusive scan: 1 block x 1024 threads, items-per-thread
__global__ __launch_bounds__(1024) void k_scan(const int* __restrict__ counts,
                                               int* __restrict__ off, int n) {
    __shared__ int sh[1024];
    int tid = threadIdx.x;
    int items = (n + 1023) >> 10;
    int base = tid * items;

    int s = 0;
    for (int i = 0; i < items; ++i) {
        int idx = base + i;
        s += (idx < n) ? counts[idx] : 0;
    }
    sh[tid] = s;
    __syncthreads();
    for (int ofs = 1; ofs < 1024; ofs <<= 1) {
        int t = (tid >= ofs) ? sh[tid - ofs] : 0;
        __syncthreads();
        sh[tid] += t;
        __syncthreads();
    }
    int run = sh[tid] - s;                 // exclusive prefix
    for (int i = 0; i < items; ++i) {
        int idx = base + i;
        if (idx < n) { off[idx] = run; run += counts[idx]; }
    }
    if (tid == 1023) off[n] = sh[1023];    // total = E
}

// fill by decrementing the still-intact histogram (order-free segments)
__global__ __launch_bounds__(256) void k_fill(const int2* __restrict__ Li,
                                              const int* __restrict__ row_off,
                                              int* __restrict__ counts,
                                              int* __restrict__ csr_col, int E) {
    int e = blockIdx.x * 256 + threadIdx.x;
    if (e < E) {
        int2 rc = Li[e];
        int idx = atomicSub(&counts[rc.x], 1) - 1;
        csr_col[row_off[rc.x] + idx] = rc.y;
    }
}

// --- heavy kernel: one wave per (b, row) ---
__global__ __launch_bounds__(256) void k_row(
    const int* __restrict__ row_off, const int* __restrict__ csr_col,
    const float* __restrict__ tf, const float4* __restrict__ node4,
    const float2* __restrict__ rpack,
    const float* __restrict__ x_state, const float* __restrict__ self_act,
    const float* __restrict__ Xs,
    const float* __restrict__ sws_p, const float* __restrict__ swn_p,
    const float* __restrict__ iws_p, const float* __restrict__ iwn_p,
    float* __restrict__ out_state, float* __restrict__ out_infl, int N)
{
    int lane = threadIdx.x & 63;
    int r = blockIdx.x * 4 + __builtin_amdgcn_readfirstlane(threadIdx.x >> 6);
    int b = (r >= N) ? 1 : 0;
    int n = r - b * N;

    int beg = row_off[n], end = row_off[n + 1];   // uniform -> s_load
    int cnt = end - beg;

    float2 rp = rpack[r];
    float er = rp.x, sr = rp.y;
    const float4* nbp = node4 + (size_t)b * N;
    const float* tfb = tf + ((size_t)b * N << 6);

    float tsel = tfb[((size_t)n << 6) + lane];    // issued early

    float mrun = -3.0e38f, l = 0.f, acc = 0.f, sacc = 0.f;

    for (int q = beg; q < end; q += 64) {
        int idx = q + lane;
        bool act = idx < end;
        int c = csr_col[act ? idx : (end - 1)];
        float4 ns = nbp[c];                       // {e_c, s_c, xs, gate}

        float lgs = sr + ns.y;
        lgs = (lgs > 0.f) ? lgs : 0.02f * lgs;
        sacc += act ? lgs * ns.z : 0.f;

        float lg = act ? (er + ns.x) : -3.0e38f;
        lg = (lg > 0.f) ? lg : 0.2f * lg;
        float M = lg;
#pragma unroll
        for (int m = 1; m < 64; m <<= 1) M = fmaxf(M, __shfl_xor(M, m, 64));
        float nm = fmaxf(mrun, M);
        float scale = __expf(mrun - nm);          // first chunk: 0
        float pp = __expf(lg - nm);               // inactive lanes -> 0
        float wgt = pp * ns.w;                    // fold gate
        float ps = pp;
#pragma unroll
        for (int m = 1; m < 64; m <<= 1) ps += __shfl_xor(ps, m, 64);
        l = fmaf(l, scale, ps);
        acc *= scale;
        mrun = nm;

        // phase 2: scalarized — col & weight to SGPR, scalar-pipe addressing
        int cc = end - q; cc = (cc > 64) ? 64 : cc;
        int cc4 = (cc + 3) & ~3;                  // pad lanes have wgt == 0
        for (int k = 0; k < cc4; k += 4) {
#pragma unroll
            for (int j = 0; j < 4; ++j) {
                int cs = __builtin_amdgcn_readlane(c, k + j);
                float ws = rl_f(wgt, k + j);
                const float* rowp = tfb + ((size_t)(unsigned)cs << 6);
                acc = fmaf(ws, rowp[lane], acc);
            }
        }
    }

    float En = (cnt > 0) ? acc / l : 0.f;

    float oi = fmaf(iwn_p[0], En, iws_p[0] * tsel);
    out_infl[(size_t)r * 64 + lane] = elu_f(oi);

#pragma unroll
    for (int m = 1; m < 64; m <<= 1) sacc += __shfl_xor(sacc, m, 64);
    if (lane == 0) {
        float Sn = sacc + self_act[n];
        float su = elu_f(fmaf(swn_p[0], Sn, sws_p[0] * x_state[r]));
        float X = Xs[r];
        out_state[r] = fmaf(su, 1.f - X, X);
    }
}

extern "C" void kernel_launch(void* const* d_in, const int* in_sizes, int n_in,
                              void* d_out, int out_size, void* d_ws, size_t ws_size,
                              hipStream_t stream) {
    const float* x_state  = (const float*)d_in[0];
    const float* x_infl   = (const float*)d_in[1];
    const int*   L_ind    = (const int*)d_in[2];
    // d_in[3] = L_values: unused by the reference
    const float* self_act = (const float*)d_in[4];
    const float* Xs       = (const float*)d_in[5];
    const float* Wg       = (const float*)d_in[6];
    const float* sbeta    = (const float*)d_in[7];
    const float* sws      = (const float*)d_in[8];
    const float* swn      = (const float*)d_in[9];
    const float* w1       = (const float*)d_in[10];
    const float* b1       = (const float*)d_in[11];
    const float* w2       = (const float*)d_in[12];
    const float* b2       = (const float*)d_in[13];
    const float* iatt     = (const float*)d_in[14];
    const float* iws      = (const float*)d_in[15];
    const float* iwn      = (const float*)d_in[16];

    const int N  = in_sizes[4];        // 50000
    const int BN = in_sizes[0];        // 100000
    const int E  = in_sizes[2] / 2;    // 800000

    char* p = (char*)d_ws;
    auto alloc = [&](size_t bytes) {
        void* q = (void*)p;
        p += (bytes + 255) & ~(size_t)255;
        return q;
    };
    float*  tf      = (float*) alloc((size_t)BN * 64 * 4);  // 25.6 MB
    float4* node4   = (float4*)alloc((size_t)BN * 16);      //  1.6 MB
    float2* rpack   = (float2*)alloc((size_t)BN * 8);       //  0.8 MB
    int*    counts  = (int*)   alloc((size_t)N * 4);
    int*    row_off = (int*)   alloc((size_t)(N + 1) * 4);
    int*    csr_col = (int*)   alloc((size_t)E * 4);        //  3.2 MB

    hipMemsetAsync(counts, 0, (size_t)N * 4, stream);

    int ge = (E + 255) / 256;
    k_hist<<<ge, 256, 0, stream>>>((const int2*)L_ind, counts, E);

    k_gemm<<<(BN + 127) / 128, 256, 0, stream>>>(x_infl, Wg, tf, BN);
    k_dots<<<(BN + 255) / 256, 256, 0, stream>>>(tf, x_state, sbeta, iatt,
                                                 w1, b1, w2, b2,
                                                 node4, rpack, BN);

    k_scan<<<1, 1024, 0, stream>>>(counts, row_off, N);
    k_fill<<<ge, 256, 0, stream>>>((const int2*)L_ind, row_off, counts, csr_col, E);

    k_row<<<BN / 4, 256, 0, stream>>>(row_off, csr_col, tf, node4, rpack,
                                      x_state, self_act, Xs,
                                      sws, swn, iws, iwn,
                                      (float*)d_out, (float*)d_out + BN, N);
}

// Round 4
// 333.733 us; speedup vs baseline: 1.2335x; 1.2335x over previous
//
#include <hip/hip_runtime.h>
#include <math.h>

// ---------------------------------------------------------------------------
// GraphConvolution: B=2, N=50000, D=64, E=800000, H=32
// R4: revert scan to 3-dispatch multi-block form (R3's single-block scan ran
//     on ONE CU: 93 us). scan3 additionally writes a cursor array so k_fill
//     needs a single atomicAdd (absolute slot), no extra row_off load.
// ---------------------------------------------------------------------------

__device__ __forceinline__ float elu_f(float x) {
    return x > 0.f ? x : __expf(x) - 1.f;
}

__device__ __forceinline__ float rl_f(float v, int k) {
    return __uint_as_float(__builtin_amdgcn_readlane(__float_as_uint(v), k));
}

// --- tf = x_infl @ W : wave = 32 rows, lane = output column ---
__global__ __launch_bounds__(256) void k_gemm(
    const float* __restrict__ x_infl, const float* __restrict__ Wg,
    float* __restrict__ tf, int BN)
{
    int lane = threadIdx.x & 63;
    int wid  = __builtin_amdgcn_readfirstlane(threadIdx.x >> 6);
    int rbase = (blockIdx.x * 4 + wid) * 32;

    float wcol[64];                        // W[:, lane]
#pragma unroll
    for (int k = 0; k < 64; ++k) wcol[k] = Wg[k * 64 + lane];

    for (int bb = 0; bb < 4; ++bb) {       // 4 batches of 8 rows
        int r0 = rbase + bb * 8;
        float xb[8], acc[8];
#pragma unroll
        for (int i = 0; i < 8; ++i) {
            int rr = r0 + i; rr = (rr < BN) ? rr : BN - 1;
            xb[i] = x_infl[((size_t)rr << 6) + lane];
            acc[i] = 0.f;
        }
#pragma unroll
        for (int k = 0; k < 64; ++k) {
#pragma unroll
            for (int i = 0; i < 8; ++i)
                acc[i] = fmaf(rl_f(xb[i], k), wcol[k], acc[i]);
        }
#pragma unroll
        for (int i = 0; i < 8; ++i)
            if (r0 + i < BN) tf[(size_t)(r0 + i) * 64 + lane] = acc[i];
    }
}

// --- per-row dots (s_r,s_c,e_r,e_c) + gate MLP; thread = row ---
__global__ __launch_bounds__(256) void k_dots(
    const float* __restrict__ tf, const float* __restrict__ x_state,
    const float* __restrict__ sbeta, const float* __restrict__ iatt,
    const float* __restrict__ w1, const float* __restrict__ b1,
    const float* __restrict__ w2, const float* __restrict__ b2,
    float4* __restrict__ node4, float2* __restrict__ rpack, int BN)
{
    int r = blockIdx.x * 256 + threadIdx.x;
    int rr = (r < BN) ? r : BN - 1;
    const float* t = tf + ((size_t)rr << 6);

    float srv = 0.f, scv = 0.f, erv = 0.f, ecv = 0.f;
#pragma unroll
    for (int k = 0; k < 64; k += 4) {
        float4 tv  = *(const float4*)(t + k);
        float4 bsr = *(const float4*)(sbeta + k);
        float4 bsc = *(const float4*)(sbeta + 64 + k);
        float4 ber = *(const float4*)(iatt + k);
        float4 bec = *(const float4*)(iatt + 64 + k);
        srv += tv.x * bsr.x + tv.y * bsr.y + tv.z * bsr.z + tv.w * bsr.w;
        scv += tv.x * bsc.x + tv.y * bsc.y + tv.z * bsc.z + tv.w * bsc.w;
        erv += tv.x * ber.x + tv.y * ber.y + tv.z * ber.z + tv.w * ber.w;
        ecv += tv.x * bec.x + tv.y * bec.y + tv.z * bec.z + tv.w * bec.w;
    }

    float xs = x_state[rr];
    float tacc = b2[0];
#pragma unroll
    for (int h = 0; h < 32; ++h)
        tacc = fmaf(elu_f(fmaf(xs, w1[h], b1[h])), w2[h], tacc);
    float gate = elu_f(tacc);

    if (r < BN) {
        node4[r] = make_float4(ecv, scv, xs, gate);   // {e_c, s_c, xs, gate}
        rpack[r] = make_float2(erv, srv);             // {e_r, s_r}
    }
}

// --- CSR build ---
__global__ __launch_bounds__(256) void k_hist(const int2* __restrict__ Li,
                                              int* __restrict__ counts, int E) {
    int e = blockIdx.x * 256 + threadIdx.x;
    if (e < E) atomicAdd(&counts[Li[e].x], 1);
}

__global__ __launch_bounds__(256) void k_scan1(const int* __restrict__ counts,
                                               int* __restrict__ off,
                                               int* __restrict__ bsum, int n) {
    __shared__ int sa[256], sb[256];
    int tid = threadIdx.x, idx = blockIdx.x * 256 + tid;
    int v = (idx < n) ? counts[idx] : 0;
    sa[tid] = v; __syncthreads();
    int *src = sa, *dst = sb;
    for (int ofs = 1; ofs < 256; ofs <<= 1) {
        int t = src[tid] + ((tid >= ofs) ? src[tid - ofs] : 0);
        dst[tid] = t; __syncthreads();
        int* tmp = src; src = dst; dst = tmp;
    }
    int inc = src[tid];
    if (idx < n) off[idx] = inc - v;           // block-local exclusive
    if (tid == 255) bsum[blockIdx.x] = inc;    // block total
}

__global__ __launch_bounds__(256) void k_scan2(int* __restrict__ bsum, int nb) {
    __shared__ int sa[256], sb[256];
    int tid = threadIdx.x;
    int v = (tid < nb) ? bsum[tid] : 0;
    sa[tid] = v; __syncthreads();
    int *src = sa, *dst = sb;
    for (int ofs = 1; ofs < 256; ofs <<= 1) {
        int t = src[tid] + ((tid >= ofs) ? src[tid - ofs] : 0);
        dst[tid] = t; __syncthreads();
        int* tmp = src; src = dst; dst = tmp;
    }
    if (tid < nb) bsum[tid] = src[tid] - v;    // exclusive block bases
}

// writes final offsets AND a cursor copy (k_fill atomically bumps cursor)
__global__ __launch_bounds__(256) void k_scan3(int* __restrict__ off,
                                               int* __restrict__ cursor,
                                               const int* __restrict__ bsum,
                                               int n, int total) {
    int idx = blockIdx.x * 256 + threadIdx.x;
    if (idx < n) {
        int v = off[idx] + bsum[blockIdx.x];
        off[idx] = v;
        cursor[idx] = v;
    }
    if (idx == 0) off[n] = total;
}

// single atomicAdd gives the absolute slot (within-row order arbitrary — ok)
__global__ __launch_bounds__(256) void k_fill(const int2* __restrict__ Li,
                                              int* __restrict__ cursor,
                                              int* __restrict__ csr_col, int E) {
    int e = blockIdx.x * 256 + threadIdx.x;
    if (e < E) {
        int2 rc = Li[e];
        int p = atomicAdd(&cursor[rc.x], 1);
        csr_col[p] = rc.y;
    }
}

// --- heavy kernel: one wave per (b, row) ---
__global__ __launch_bounds__(256) void k_row(
    const int* __restrict__ row_off, const int* __restrict__ csr_col,
    const float* __restrict__ tf, const float4* __restrict__ node4,
    const float2* __restrict__ rpack,
    const float* __restrict__ x_state, const float* __restrict__ self_act,
    const float* __restrict__ Xs,
    const float* __restrict__ sws_p, const float* __restrict__ swn_p,
    const float* __restrict__ iws_p, const float* __restrict__ iwn_p,
    float* __restrict__ out_state, float* __restrict__ out_infl, int N)
{
    int lane = threadIdx.x & 63;
    int r = blockIdx.x * 4 + __builtin_amdgcn_readfirstlane(threadIdx.x >> 6);
    int b = (r >= N) ? 1 : 0;
    int n = r - b * N;

    int beg = row_off[n], end = row_off[n + 1];   // uniform -> s_load
    int cnt = end - beg;

    float2 rp = rpack[r];
    float er = rp.x, sr = rp.y;
    const float4* nbp = node4 + (size_t)b * N;
    const float* tfb = tf + ((size_t)b * N << 6);

    float tsel = tfb[((size_t)n << 6) + lane];    // issued early

    float mrun = -3.0e38f, l = 0.f, acc = 0.f, sacc = 0.f;

    for (int q = beg; q < end; q += 64) {
        int idx = q + lane;
        bool act = idx < end;
        int c = csr_col[act ? idx : (end - 1)];
        float4 ns = nbp[c];                       // {e_c, s_c, xs, gate}

        float lgs = sr + ns.y;
        lgs = (lgs > 0.f) ? lgs : 0.02f * lgs;
        sacc += act ? lgs * ns.z : 0.f;

        float lg = act ? (er + ns.x) : -3.0e38f;
        lg = (lg > 0.f) ? lg : 0.2f * lg;
        float M = lg;
#pragma unroll
        for (int m = 1; m < 64; m <<= 1) M = fmaxf(M, __shfl_xor(M, m, 64));
        float nm = fmaxf(mrun, M);
        float scale = __expf(mrun - nm);          // first chunk: 0
        float pp = __expf(lg - nm);               // inactive lanes -> 0
        float wgt = pp * ns.w;                    // fold gate
        float ps = pp;
#pragma unroll
        for (int m = 1; m < 64; m <<= 1) ps += __shfl_xor(ps, m, 64);
        l = fmaf(l, scale, ps);
        acc *= scale;
        mrun = nm;

        // phase 2: scalarized — col & weight to SGPR, scalar-pipe addressing
        int cc = end - q; cc = (cc > 64) ? 64 : cc;
        int cc4 = (cc + 3) & ~3;                  // pad lanes have wgt == 0
        for (int k = 0; k < cc4; k += 4) {
#pragma unroll
            for (int j = 0; j < 4; ++j) {
                int cs = __builtin_amdgcn_readlane(c, k + j);
                float ws = rl_f(wgt, k + j);
                const float* rowp = tfb + ((size_t)(unsigned)cs << 6);
                acc = fmaf(ws, rowp[lane], acc);
            }
        }
    }

    float En = (cnt > 0) ? acc / l : 0.f;

    float oi = fmaf(iwn_p[0], En, iws_p[0] * tsel);
    out_infl[(size_t)r * 64 + lane] = elu_f(oi);

#pragma unroll
    for (int m = 1; m < 64; m <<= 1) sacc += __shfl_xor(sacc, m, 64);
    if (lane == 0) {
        float Sn = sacc + self_act[n];
        float su = elu_f(fmaf(swn_p[0], Sn, sws_p[0] * x_state[r]));
        float X = Xs[r];
        out_state[r] = fmaf(su, 1.f - X, X);
    }
}

extern "C" void kernel_launch(void* const* d_in, const int* in_sizes, int n_in,
                              void* d_out, int out_size, void* d_ws, size_t ws_size,
                              hipStream_t stream) {
    const float* x_state  = (const float*)d_in[0];
    const float* x_infl   = (const float*)d_in[1];
    const int*   L_ind    = (const int*)d_in[2];
    // d_in[3] = L_values: unused by the reference
    const float* self_act = (const float*)d_in[4];
    const float* Xs       = (const float*)d_in[5];
    const float* Wg       = (const float*)d_in[6];
    const float* sbeta    = (const float*)d_in[7];
    const float* sws      = (const float*)d_in[8];
    const float* swn      = (const float*)d_in[9];
    const float* w1       = (const float*)d_in[10];
    const float* b1       = (const float*)d_in[11];
    const float* w2       = (const float*)d_in[12];
    const float* b2       = (const float*)d_in[13];
    const float* iatt     = (const float*)d_in[14];
    const float* iws      = (const float*)d_in[15];
    const float* iwn      = (const float*)d_in[16];

    const int N  = in_sizes[4];        // 50000
    const int BN = in_sizes[0];        // 100000
    const int E  = in_sizes[2] / 2;    // 800000

    char* p = (char*)d_ws;
    auto alloc = [&](size_t bytes) {
        void* q = (void*)p;
        p += (bytes + 255) & ~(size_t)255;
        return q;
    };
    float*  tf      = (float*) alloc((size_t)BN * 64 * 4);  // 25.6 MB
    float4* node4   = (float4*)alloc((size_t)BN * 16);      //  1.6 MB
    float2* rpack   = (float2*)alloc((size_t)BN * 8);       //  0.8 MB
    int*    counts  = (int*)   alloc((size_t)N * 4);
    int*    cursor  = (int*)   alloc((size_t)N * 4);
    int*    row_off = (int*)   alloc((size_t)(N + 1) * 4);
    int*    bsum    = (int*)   alloc(1024 * 4);
    int*    csr_col = (int*)   alloc((size_t)E * 4);        //  3.2 MB

    hipMemsetAsync(counts, 0, (size_t)N * 4, stream);

    int ge = (E + 255) / 256;
    k_hist<<<ge, 256, 0, stream>>>((const int2*)L_ind, counts, E);

    k_gemm<<<(BN + 127) / 128, 256, 0, stream>>>(x_infl, Wg, tf, BN);
    k_dots<<<(BN + 255) / 256, 256, 0, stream>>>(tf, x_state, sbeta, iatt,
                                                 w1, b1, w2, b2,
                                                 node4, rpack, BN);

    int nb = (N + 255) / 256;
    k_scan1<<<nb, 256, 0, stream>>>(counts, row_off, bsum, N);
    k_scan2<<<1, 256, 0, stream>>>(bsum, nb);
    k_scan3<<<nb, 256, 0, stream>>>(row_off, cursor, bsum, N, E);

    k_fill<<<ge, 256, 0, stream>>>((const int2*)L_ind, cursor, csr_col, E);

    k_row<<<BN / 4, 256, 0, stream>>>(row_off, csr_col, tf, node4, rpack,
                                      x_state, self_act, Xs,
                                      sws, swn, iws, iwn,
                                      (float*)d_out, (float*)d_out + BN, N);
}